// Round 1
// baseline (394.790 us; speedup 1.0000x reference)
//
#include <hip/hip_runtime.h>

// HDVLUT: MuLUT-style 2x SR with 3 LUTs (h/d/v) over 8 rotation passes,
// algebraically folded into a single fused pass in the original frame.
//
// For output 2x2 block owned by LR pixel (y,x):
//   a = I[y,x] always; partner b per pass is a clamped neighbor:
//     h: r=0 -> E,  r=2 -> W
//     v: r=0 -> S,  r=2 -> N
//     d: r=0 -> SE, r=1 -> SW, r=2 -> NW, r=3 -> NE
//   Accumulator permutation per rotation r (k = 2*s + t, s=row,t=col in 2x2):
//     r=0: acc[k] += w[k]
//     r=1: acc += {w2, w0, w3, w1}
//     r=2: acc[k] += w[3-k]
//     r=3: acc += {w1, w3, w0, w2}
//   out = acc / 2.

__global__ __launch_bounds__(256) void hdvlut_kernel(
    const int* __restrict__ img,
    const float4* __restrict__ wh,
    const float4* __restrict__ wd,
    const float4* __restrict__ wv,
    float* __restrict__ out)
{
    int idx = blockIdx.x * 256 + threadIdx.x;
    int x = idx & 511;
    int y = (idx >> 9) & 511;
    int b = idx >> 18;

    const int* I = img + ((size_t)b << 18);

    int row = y << 9;
    int xm = (x > 0)   ? x - 1 : 0;
    int xp = (x < 511) ? x + 1 : 511;
    int ym = (y > 0)   ? y - 1 : 0;
    int yp = (y < 511) ? y + 1 : 511;
    int rN = ym << 9;
    int rS = yp << 9;

    int a  = I[row | x];
    int E  = I[row | xp];
    int W_ = I[row | xm];
    int S  = I[rS  | x ];
    int N_ = I[rN  | x ];
    int SE = I[rS  | xp];
    int SW = I[rS  | xm];
    int NW = I[rN  | xm];
    int NE = I[rN  | xp];

    int aL = a << 8;  // a * L, L = 256

    float4 t;
    float ax, ay, az, aw;

    // h, r=0 (E): identity
    t = wh[aL + E];
    ax = t.x; ay = t.y; az = t.z; aw = t.w;
    // h, r=2 (W): reversed
    t = wh[aL + W_];
    ax += t.w; ay += t.z; az += t.y; aw += t.x;
    // v, r=0 (S): identity
    t = wv[aL + S];
    ax += t.x; ay += t.y; az += t.z; aw += t.w;
    // v, r=2 (N): reversed
    t = wv[aL + N_];
    ax += t.w; ay += t.z; az += t.y; aw += t.x;
    // d, r=0 (SE): identity
    t = wd[aL + SE];
    ax += t.x; ay += t.y; az += t.z; aw += t.w;
    // d, r=1 (SW): {w2, w0, w3, w1}
    t = wd[aL + SW];
    ax += t.z; ay += t.x; az += t.w; aw += t.y;
    // d, r=2 (NW): reversed
    t = wd[aL + NW];
    ax += t.w; ay += t.z; az += t.y; aw += t.x;
    // d, r=3 (NE): {w1, w3, w0, w2}
    t = wd[aL + NE];
    ax += t.y; ay += t.w; az += t.x; aw += t.z;

    ax *= 0.5f; ay *= 0.5f; az *= 0.5f; aw *= 0.5f;

    // Output block: rows 2y, 2y+1; cols 2x, 2x+1 of a 1024x1024 image.
    size_t obase = ((((size_t)b << 10) + (y << 1)) << 10) + (x << 1);
    *(float2*)(out + obase)        = make_float2(ax, ay);
    *(float2*)(out + obase + 1024) = make_float2(az, aw);
}

extern "C" void kernel_launch(void* const* d_in, const int* in_sizes, int n_in,
                              void* d_out, int out_size, void* d_ws, size_t ws_size,
                              hipStream_t stream) {
    const int*    img = (const int*)d_in[0];
    const float4* wh  = (const float4*)d_in[1];
    const float4* wd  = (const float4*)d_in[2];
    const float4* wv  = (const float4*)d_in[3];
    float* out = (float*)d_out;

    int total  = in_sizes[0];          // B * 512 * 512
    int blocks = total / 256;
    hipLaunchKernelGGL(hdvlut_kernel, dim3(blocks), dim3(256), 0, stream,
                       img, wh, wd, wv, out);
}

// Round 2
// 394.573 us; speedup vs baseline: 1.0005x; 1.0005x over previous
//
#include <hip/hip_runtime.h>

// HDVLUT: MuLUT-style 2x SR with 3 LUTs (h/d/v) over 8 rotation passes,
// algebraically folded into a single fused pass in the original frame.
//
// For output 2x2 block owned by LR pixel (y,x):
//   a = I[y,x] always; partner b per pass is a clamped neighbor:
//     h: r=0 -> E,  r=2 -> W
//     v: r=0 -> S,  r=2 -> N
//     d: r=0 -> SE, r=1 -> SW, r=2 -> NW, r=3 -> NE
//   Accumulator permutation per rotation r (k = 2*s + t, s=row,t=col in 2x2):
//     r=0: acc[k] += w[k]
//     r=1: acc += {w2, w0, w3, w1}
//     r=2: acc[k] += w[3-k]
//     r=3: acc += {w1, w3, w0, w2}
//   out = acc / 2.
//
// R1 lesson: compiler minimized to 20 VGPRs and serialized the 8 gathers
// (MLP~1, VALUBusy 6%, 284us). Force all 8 gathers in flight with a
// scheduling barrier between the load cluster and the accumulation.

__global__ __launch_bounds__(256) void hdvlut_kernel(
    const int* __restrict__ img,
    const float4* __restrict__ wh,
    const float4* __restrict__ wd,
    const float4* __restrict__ wv,
    float* __restrict__ out)
{
    int idx = blockIdx.x * 256 + threadIdx.x;
    int x = idx & 511;
    int y = (idx >> 9) & 511;
    int b = idx >> 18;

    const int* I = img + ((size_t)b << 18);

    int row = y << 9;
    int xm = (x > 0)   ? x - 1 : 0;
    int xp = (x < 511) ? x + 1 : 511;
    int ym = (y > 0)   ? y - 1 : 0;
    int yp = (y < 511) ? y + 1 : 511;
    int rN = ym << 9;
    int rS = yp << 9;

    int a  = I[row | x];
    int E  = I[row | xp];
    int W_ = I[row | xm];
    int S  = I[rS  | x ];
    int N_ = I[rN  | x ];
    int SE = I[rS  | xp];
    int SW = I[rS  | xm];
    int NW = I[rN  | xm];
    int NE = I[rN  | xp];

    int aL = a << 8;  // a * L, L = 256

    // --- load cluster: all 8 gathers issued back-to-back, 8-deep MLP ---
    float4 t0 = wh[aL + E ];   // h r=0, identity
    float4 t1 = wh[aL + W_];   // h r=2, reversed
    float4 t2 = wv[aL + S ];   // v r=0, identity
    float4 t3 = wv[aL + N_];   // v r=2, reversed
    float4 t4 = wd[aL + SE];   // d r=0, identity
    float4 t5 = wd[aL + SW];   // d r=1, {2,0,3,1}
    float4 t6 = wd[aL + NW];   // d r=2, reversed
    float4 t7 = wd[aL + NE];   // d r=3, {1,3,0,2}
    // Scheduling fence: keep the 8 load instructions clustered above the
    // accumulation so the backend emits decreasing vmcnt waits (MLP=8)
    // instead of serializing to save VGPRs.
    asm volatile("" ::: "memory");

    float ax, ay, az, aw;
    ax  = t0.x; ay  = t0.y; az  = t0.z; aw  = t0.w;
    ax += t1.w; ay += t1.z; az += t1.y; aw += t1.x;
    ax += t2.x; ay += t2.y; az += t2.z; aw += t2.w;
    ax += t3.w; ay += t3.z; az += t3.y; aw += t3.x;
    ax += t4.x; ay += t4.y; az += t4.z; aw += t4.w;
    ax += t5.z; ay += t5.x; az += t5.w; aw += t5.y;
    ax += t6.w; ay += t6.z; az += t6.y; aw += t6.x;
    ax += t7.y; ay += t7.w; az += t7.x; aw += t7.z;

    ax *= 0.5f; ay *= 0.5f; az *= 0.5f; aw *= 0.5f;

    // Output block: rows 2y, 2y+1; cols 2x, 2x+1 of a 1024x1024 image.
    size_t obase = ((((size_t)b << 10) + (y << 1)) << 10) + (x << 1);
    *(float2*)(out + obase)        = make_float2(ax, ay);
    *(float2*)(out + obase + 1024) = make_float2(az, aw);
}

extern "C" void kernel_launch(void* const* d_in, const int* in_sizes, int n_in,
                              void* d_out, int out_size, void* d_ws, size_t ws_size,
                              hipStream_t stream) {
    const int*    img = (const int*)d_in[0];
    const float4* wh  = (const float4*)d_in[1];
    const float4* wd  = (const float4*)d_in[2];
    const float4* wv  = (const float4*)d_in[3];
    float* out = (float*)d_out;

    int total  = in_sizes[0];          // B * 512 * 512
    int blocks = total / 256;
    hipLaunchKernelGGL(hdvlut_kernel, dim3(blocks), dim3(256), 0, stream,
                       img, wh, wd, wv, out);
}

// Round 3
// 390.687 us; speedup vs baseline: 1.0105x; 1.0099x over previous
//
#include <hip/hip_runtime.h>

// HDVLUT: MuLUT-style 2x SR with 3 LUTs (h/d/v) over 8 rotation passes,
// algebraically folded into a single fused pass in the original frame.
//
// For output 2x2 block owned by LR pixel (y,x):
//   a = I[y,x] always; partner b per pass is a clamped neighbor:
//     h: r=0 -> E,  r=2 -> W   | v: r=0 -> S,  r=2 -> N
//     d: r=0 -> SE, r=1 -> SW, r=2 -> NW, r=3 -> NE
//   Accumulator permutation per rotation r:
//     r=0: +{w0,w1,w2,w3}  r=1: +{w2,w0,w3,w1}
//     r=2: +{w3,w2,w1,w0}  r=3: +{w1,w3,w0,w2}
//   out = acc / 2.
//
// R1/R2 lesson: compiler minimized to 20 VGPRs and serialized the 8 LUT
// gathers (MLP~1 -> 282us, VALUBusy 6%). A compiler-level memory fence did
// NOT stop the machine scheduler from interleaving VALU adds between loads.
// R3: force MLP=8 with one inline-asm block issuing all 8 global_load_dwordx4
// back-to-back with a single trailing s_waitcnt.

typedef float f4 __attribute__((ext_vector_type(4)));

__global__ __launch_bounds__(256) void hdvlut_kernel(
    const int* __restrict__ img,
    const float4* __restrict__ wh,
    const float4* __restrict__ wd,
    const float4* __restrict__ wv,
    float* __restrict__ out)
{
    int idx = blockIdx.x * 256 + threadIdx.x;
    int x = idx & 511;
    int y = (idx >> 9) & 511;
    int b = idx >> 18;

    const int* I = img + ((size_t)b << 18);

    int row = y << 9;
    int xm = (x > 0)   ? x - 1 : 0;
    int xp = (x < 511) ? x + 1 : 511;
    int ym = (y > 0)   ? y - 1 : 0;
    int yp = (y < 511) ? y + 1 : 511;
    int rN = ym << 9;
    int rS = yp << 9;

    int a  = I[row | x];
    int E  = I[row | xp];
    int W_ = I[row | xm];
    int S  = I[rS  | x ];
    int N_ = I[rN  | x ];
    int SE = I[rS  | xp];
    int SW = I[rS  | xm];
    int NW = I[rN  | xm];
    int NE = I[rN  | xp];

    int aL = a << 8;  // a * L, L = 256

    const float4* p0 = wh + (aL + E );  // h r=0, identity
    const float4* p1 = wh + (aL + W_);  // h r=2, reversed
    const float4* p2 = wv + (aL + S );  // v r=0, identity
    const float4* p3 = wv + (aL + N_);  // v r=2, reversed
    const float4* p4 = wd + (aL + SE);  // d r=0, identity
    const float4* p5 = wd + (aL + SW);  // d r=1, {2,0,3,1}
    const float4* p6 = wd + (aL + NW);  // d r=2, reversed
    const float4* p7 = wd + (aL + NE);  // d r=3, {1,3,0,2}

    f4 t0, t1, t2, t3, t4, t5, t6, t7;
    // All 8 gathers issued back-to-back: MLP=8, one latency exposure instead
    // of eight. Early-clobber outputs force 32 result VGPRs live at once so
    // the register allocator cannot re-serialize.
    asm volatile(
        "global_load_dwordx4 %0, %8, off\n\t"
        "global_load_dwordx4 %1, %9, off\n\t"
        "global_load_dwordx4 %2, %10, off\n\t"
        "global_load_dwordx4 %3, %11, off\n\t"
        "global_load_dwordx4 %4, %12, off\n\t"
        "global_load_dwordx4 %5, %13, off\n\t"
        "global_load_dwordx4 %6, %14, off\n\t"
        "global_load_dwordx4 %7, %15, off\n\t"
        "s_waitcnt vmcnt(0)"
        : "=&v"(t0), "=&v"(t1), "=&v"(t2), "=&v"(t3),
          "=&v"(t4), "=&v"(t5), "=&v"(t6), "=&v"(t7)
        : "v"(p0), "v"(p1), "v"(p2), "v"(p3),
          "v"(p4), "v"(p5), "v"(p6), "v"(p7));

    float ax, ay, az, aw;
    ax  = t0.x; ay  = t0.y; az  = t0.z; aw  = t0.w;
    ax += t1.w; ay += t1.z; az += t1.y; aw += t1.x;
    ax += t2.x; ay += t2.y; az += t2.z; aw += t2.w;
    ax += t3.w; ay += t3.z; az += t3.y; aw += t3.x;
    ax += t4.x; ay += t4.y; az += t4.z; aw += t4.w;
    ax += t5.z; ay += t5.x; az += t5.w; aw += t5.y;
    ax += t6.w; ay += t6.z; az += t6.y; aw += t6.x;
    ax += t7.y; ay += t7.w; az += t7.x; aw += t7.z;

    ax *= 0.5f; ay *= 0.5f; az *= 0.5f; aw *= 0.5f;

    // Output block: rows 2y, 2y+1; cols 2x, 2x+1 of a 1024x1024 image.
    size_t obase = ((((size_t)b << 10) + (y << 1)) << 10) + (x << 1);
    *(float2*)(out + obase)        = make_float2(ax, ay);
    *(float2*)(out + obase + 1024) = make_float2(az, aw);
}

extern "C" void kernel_launch(void* const* d_in, const int* in_sizes, int n_in,
                              void* d_out, int out_size, void* d_ws, size_t ws_size,
                              hipStream_t stream) {
    const int*    img = (const int*)d_in[0];
    const float4* wh  = (const float4*)d_in[1];
    const float4* wd  = (const float4*)d_in[2];
    const float4* wv  = (const float4*)d_in[3];
    float* out = (float*)d_out;

    int total  = in_sizes[0];          // B * 512 * 512
    int blocks = total / 256;
    hipLaunchKernelGGL(hdvlut_kernel, dim3(blocks), dim3(256), 0, stream,
                       img, wh, wd, wv, out);
}